// Round 19
// baseline (105.440 us; speedup 1.0000x reference)
//
#include <hip/hip_runtime.h>
#include <hip/hip_bf16.h>
#include <math.h>

typedef _Float16 f16x8 __attribute__((ext_vector_type(8)));
typedef _Float16 f16x4 __attribute__((ext_vector_type(4)));
typedef __fp16   hf4  __attribute__((ext_vector_type(4)));
typedef float    f32x4 __attribute__((ext_vector_type(4)));
typedef __bf16   bf16x8 __attribute__((ext_vector_type(8)));
typedef __bf16   bf16x4 __attribute__((ext_vector_type(4)));

#define MFMA32_F16(a,b,c)  __builtin_amdgcn_mfma_f32_16x16x32_f16((a),(b),(c),0,0,0)
#define MFMA_BF16(a,b,c)   __builtin_amdgcn_mfma_f32_16x16x32_bf16((a),(b),(c),0,0,0)

constexpr int S_LEN = 2048;
constexpr int DH    = 64;
constexpr int KBLK  = 64;
constexpr int NSTEP = S_LEN / KBLK;       // 32
constexpr float LOG2E = 1.44269504088896340736f;
constexpr size_t TILE_BYTES = 16384;      // 8KB K + 8KB V-frag per tile
constexpr size_t WS_NEED = 64ull * NSTEP * TILE_BYTES;  // 33.55 MB

__device__ __forceinline__ void gload16(const void* g, void* l) {
    __builtin_amdgcn_global_load_lds(
        (const __attribute__((address_space(1))) void*)g,
        (__attribute__((address_space(3))) void*)l, 16, 0, 0);
}

__device__ __forceinline__ float exp2_fast(float x) {
    float r;
    asm("v_exp_f32 %0, %1" : "=v"(r) : "v"(x));
    return r;
}

// reductions across the 4 lane-groups holding one q-row (l^16, l^32)
__device__ __forceinline__ float redmax_lg(float x) {
    x = fmaxf(x, __shfl_xor(x, 16));
    x = fmaxf(x, __shfl_xor(x, 32));
    return x;
}

__device__ __forceinline__ f16x4 as_f16x4(hf4 h) {
    f16x4 f;
    __builtin_memcpy(&f, &h, 8);
    return f;
}

// ---------------- pre-pass: K -> fp16 swizzled rows; V -> permuted-k A-fragments ----------------
// K tile (8KB): row-major, byte (row*128 + d*2) ^ ((row&7)<<4)
// V tile (8KB): chunk16B[(p*4+lg)*1024 + d*16]: halves[j] = V[p*32 + (j>>2)*16 + lg*4 + (j&3)][d]
//   == A-fragment of 16x16x32 MFMA under shared k-map k(lg,j) = (j>>2)*16 + lg*4 + (j&3)
__global__ __launch_bounds__(256)
void prep_kernel(const float* __restrict__ Kg, const float* __restrict__ Vg,
                 unsigned char* __restrict__ ws)
{
    __shared__ _Float16 sT[64 * 70];   // V tile staging, pitch 70 halfs

    const int blk = blockIdx.x;        // bh*32 + tile
    const int tid = threadIdx.x;
    const float* Kt = Kg + (size_t)blk * KBLK * DH;
    const float* Vt = Vg + (size_t)blk * KBLK * DH;
    char* wK = (char*)(ws + (size_t)blk * TILE_BYTES);
    char* wV = wK + 8192;

    #pragma unroll
    for (int c = 0; c < 2; ++c) {
        const int eid = tid + c * 256;         // 0..511 chunks of 8 elems
        const int row = eid >> 3;
        const int d0  = (eid & 7) * 8;
        // K: convert + pre-swizzled row-major tile
        f32x4 a = *(const f32x4*)(Kt + row * DH + d0);
        f32x4 b = *(const f32x4*)(Kt + row * DH + d0 + 4);
        f16x8 h;
        #pragma unroll
        for (int j = 0; j < 4; ++j) { h[j] = (_Float16)a[j]; h[4 + j] = (_Float16)b[j]; }
        const int koff = (row * 128 + d0 * 2) ^ ((row & 7) << 4);
        *(f16x8*)(wK + koff) = h;
        // V: convert into LDS row-major (pitch 70)
        f32x4 va = *(const f32x4*)(Vt + row * DH + d0);
        f32x4 vb = *(const f32x4*)(Vt + row * DH + d0 + 4);
        #pragma unroll
        for (int j = 0; j < 4; ++j) {
            sT[row * 70 + d0 + j]     = (_Float16)va[j];
            sT[row * 70 + d0 + 4 + j] = (_Float16)vb[j];
        }
    }
    __syncthreads();
    // build permuted-k V-fragment chunks
    #pragma unroll
    for (int c = 0; c < 2; ++c) {
        const int id  = tid + c * 256;   // 0..511
        const int p   = id >> 8;         // 0..1
        const int lgc = (id >> 6) & 3;   // 0..3
        const int d   = id & 63;
        const int kv0 = p * 32 + lgc * 4;
        f16x8 h;
        #pragma unroll
        for (int j = 0; j < 4; ++j) {
            h[j]     = sT[(kv0 + j) * 70 + d];
            h[4 + j] = sT[(kv0 + 16 + j) * 70 + d];
        }
        *(f16x8*)(wV + (p * 4 + lgc) * 1024 + d * 16) = h;
    }
}

// ---------------- main: r15 body + 3-buffer staging with counted vmcnt (T4) ----------------
__global__ __launch_bounds__(256, 3)
void attn_main(const float* __restrict__ Qg0, const unsigned char* __restrict__ ws,
               float* __restrict__ Og0)
{
    __shared__ __align__(16) _Float16 sK[3][KBLK * DH];   // 24 KB
    __shared__ __align__(16) _Float16 sV[3][KBLK * DH];   // 24 KB  (total 49152 -> 3 blocks/CU)

    const int tid  = threadIdx.x;
    const int lane = tid & 63;
    const int w    = tid >> 6;
    const int lg   = lane >> 4;
    const int li   = lane & 15;
    const int X    = (li & 7) << 4;    // K-read XOR swizzle key

    // 1024 blocks = 8 xcd * 8 bh * 16 qpairs
    const int n   = blockIdx.x;
    const int xcd = n & 7;
    const int m_  = n >> 3;            // 0..127
    const int bh  = xcd * 8 + (m_ >> 4);
    const int qp  = m_ & 15;

    const float* Qg = Qg0 + (size_t)bh * S_LEN * DH;
    float*       Og = Og0 + (size_t)bh * S_LEN * DH;
    const unsigned char* wsb = ws + (size_t)bh * NSTEP * TILE_BYTES;

    // Q fragments (fp16), pre-scaled by log2(e); two q-tiles A/B
    f16x8 qA[2], qB[2];
    {
        const int qrowA = qp * 128 + w * 16 + li;
        const float* pa = Qg + (size_t)qrowA * DH;
        const float* pb = pa + 64 * DH;
        #pragma unroll
        for (int f = 0; f < 2; ++f) {
            f32x4 a0 = *(const f32x4*)(pa + f * 32 + lg * 8);
            f32x4 a1 = *(const f32x4*)(pa + f * 32 + lg * 8 + 4);
            f32x4 b0 = *(const f32x4*)(pb + f * 32 + lg * 8);
            f32x4 b1 = *(const f32x4*)(pb + f * 32 + lg * 8 + 4);
            #pragma unroll
            for (int j = 0; j < 4; ++j) {
                qA[f][j]     = (_Float16)(a0[j] * LOG2E);
                qA[f][4 + j] = (_Float16)(a1[j] * LOG2E);
                qB[f][j]     = (_Float16)(b0[j] * LOG2E);
                qB[f][4 + j] = (_Float16)(b1[j] * LOG2E);
            }
        }
    }

    // all-ones A-fragment: layout-independent; MFMA(ones, pf, lacc) sums P over kv
    f16x8 ones;
    #pragma unroll
    for (int j = 0; j < 8; ++j) ones[j] = (_Float16)1.0f;

    f32x4 accoA[4], accoB[4];
    #pragma unroll
    for (int t = 0; t < 4; ++t) {
        accoA[t] = f32x4{0.f, 0.f, 0.f, 0.f};
        accoB[t] = f32x4{0.f, 0.f, 0.f, 0.f};
    }
    float mA = 0.f, mB = 0.f;
    f32x4 laccA = {0.f, 0.f, 0.f, 0.f};
    f32x4 laccB = {0.f, 0.f, 0.f, 0.f};

    // each wave issues 4 gload16 per stage(): 2 K chunks + 2 V chunks
    auto stage = [&](char* lkb, char* lvb, int t) {
        const unsigned char* src = wsb + (size_t)t * TILE_BYTES;
        char* lk = lkb + w * 2048;
        char* lv = lvb + w * 2048;
        const unsigned char* gk = src + w * 2048 + lane * 16;
        const unsigned char* gv = src + 8192 + w * 2048 + lane * 16;
        gload16(gk,        lk);
        gload16(gk + 1024, lk + 1024);
        gload16(gv,        lv);
        gload16(gv + 1024, lv + 1024);
    };

    // ring: pr = tile t (read), pn = tile t+1 (in flight/ready), pw = tile t+2 (write target)
    char* krp = (char*)&sK[0][0]; char* vrp = (char*)&sV[0][0];
    char* knp = (char*)&sK[1][0]; char* vnp = (char*)&sV[1][0];
    char* kwp = (char*)&sK[2][0]; char* vwp = (char*)&sV[2][0];

    // prologue: issue tiles 0 and 1; wait only own tile-0 loads (4 of tile-1 stay in flight)
    stage(krp, vrp, 0);
    stage(knp, vnp, 1);
    asm volatile("s_waitcnt vmcnt(4)" ::: "memory");
    __builtin_amdgcn_s_barrier();
    __builtin_amdgcn_sched_barrier(0);

    for (int t = 0; t < NSTEP; ++t) {
        // issue tile t+2 loads first so they overlap this step's compute
        if (t + 2 < NSTEP) stage(kwp, vwp, t + 2);

        const char* kb = krp;
        const char* vb = vrp;

        // ---- S^T - m = K Q^T + (-m) ----
        f32x4 sA[4], sB[4];
        const f32x4 cA = {-mA, -mA, -mA, -mA};
        const f32x4 cB = {-mB, -mB, -mB, -mB};
        __builtin_amdgcn_s_setprio(1);
        #pragma unroll
        for (int t4 = 0; t4 < 4; ++t4) {
            const char* kr = kb + t4 * 2048 + li * 128;
            f16x8 kf0 = *(const f16x8*)(kr + ((0 * 64 + lg * 16) ^ X));
            f16x8 kf1 = *(const f16x8*)(kr + ((1 * 64 + lg * 16) ^ X));
            f32x4 a = MFMA32_F16(kf0, qA[0], cA);
            a       = MFMA32_F16(kf1, qA[1], a);
            f32x4 b = MFMA32_F16(kf0, qB[0], cB);
            b       = MFMA32_F16(kf1, qB[1], b);
            sA[t4] = a;
            sB[t4] = b;
        }
        __builtin_amdgcn_s_setprio(0);

        // ---- lane-local max of biased scores (16 kv each) ----
        float mlA = fmaxf(fmaxf(fmaxf(sA[0][0], sA[0][1]), sA[0][2]),
                          fmaxf(fmaxf(sA[0][3], sA[1][0]), sA[1][1]));
        mlA = fmaxf(mlA, fmaxf(fmaxf(sA[1][2], sA[1][3]), sA[2][0]));
        mlA = fmaxf(mlA, fmaxf(fmaxf(sA[2][1], sA[2][2]), sA[2][3]));
        mlA = fmaxf(mlA, fmaxf(fmaxf(sA[3][0], sA[3][1]), fmaxf(sA[3][2], sA[3][3])));
        float mlB = fmaxf(fmaxf(fmaxf(sB[0][0], sB[0][1]), sB[0][2]),
                          fmaxf(fmaxf(sB[0][3], sB[1][0]), sB[1][1]));
        mlB = fmaxf(mlB, fmaxf(fmaxf(sB[1][2], sB[1][3]), sB[2][0]));
        mlB = fmaxf(mlB, fmaxf(fmaxf(sB[2][1], sB[2][2]), sB[2][3]));
        mlB = fmaxf(mlB, fmaxf(fmaxf(sB[3][0], sB[3][1]), fmaxf(sB[3][2], sB[3][3])));

        // ---- defer-max rescale: fires rarely; re-bias scores when it does ----
        if (__any(mlA > 8.f)) {
            const float rowmax = redmax_lg(mlA);
            const float delta  = fmaxf(rowmax, 0.f);
            const float sc     = exp2_fast(-delta);
            mA += delta;  laccA *= sc;
            #pragma unroll
            for (int t4 = 0; t4 < 4; ++t4) { accoA[t4] *= sc; sA[t4] -= delta; }
        }
        if (__any(mlB > 8.f)) {
            const float rowmax = redmax_lg(mlB);
            const float delta  = fmaxf(rowmax, 0.f);
            const float sc     = exp2_fast(-delta);
            mB += delta;  laccB *= sc;
            #pragma unroll
            for (int t4 = 0; t4 < 4; ++t4) { accoB[t4] *= sc; sB[t4] -= delta; }
        }

        // ---- exp2 + packed f16 convert (no scalar sum adds) ----
        f16x4 pA[4], pB[4];
        #pragma unroll
        for (int t4 = 0; t4 < 4; ++t4) {
            float a0 = exp2_fast(sA[t4][0]);
            float a1 = exp2_fast(sA[t4][1]);
            float a2 = exp2_fast(sA[t4][2]);
            float a3 = exp2_fast(sA[t4][3]);
            pA[t4] = as_f16x4(__builtin_shufflevector(
                __builtin_amdgcn_cvt_pkrtz(a0, a1),
                __builtin_amdgcn_cvt_pkrtz(a2, a3), 0, 1, 2, 3));
            float b0 = exp2_fast(sB[t4][0]);
            float b1 = exp2_fast(sB[t4][1]);
            float b2 = exp2_fast(sB[t4][2]);
            float b3 = exp2_fast(sB[t4][3]);
            pB[t4] = as_f16x4(__builtin_shufflevector(
                __builtin_amdgcn_cvt_pkrtz(b0, b1),
                __builtin_amdgcn_cvt_pkrtz(b2, b3), 0, 1, 2, 3));
        }

        f16x8 pfA0 = __builtin_shufflevector(pA[0], pA[1], 0, 1, 2, 3, 4, 5, 6, 7);
        f16x8 pfA1 = __builtin_shufflevector(pA[2], pA[3], 0, 1, 2, 3, 4, 5, 6, 7);
        f16x8 pfB0 = __builtin_shufflevector(pB[0], pB[1], 0, 1, 2, 3, 4, 5, 6, 7);
        f16x8 pfB1 = __builtin_shufflevector(pB[2], pB[3], 0, 1, 2, 3, 4, 5, 6, 7);

        // ---- O^T += V^T P^T, and l += sum(P) via ones-MFMA (independent chains) ----
        __builtin_amdgcn_s_setprio(1);
        laccA = MFMA32_F16(ones, pfA0, laccA);
        laccB = MFMA32_F16(ones, pfB0, laccB);
        #pragma unroll
        for (int t4v = 0; t4v < 4; ++t4v) {
            f16x8 vv0 = *(const f16x8*)(vb + lg * 1024 + t4v * 256 + li * 16);
            accoA[t4v] = MFMA32_F16(vv0, pfA0, accoA[t4v]);
            accoB[t4v] = MFMA32_F16(vv0, pfB0, accoB[t4v]);
            f16x8 vv1 = *(const f16x8*)(vb + 4096 + lg * 1024 + t4v * 256 + li * 16);
            accoA[t4v] = MFMA32_F16(vv1, pfA1, accoA[t4v]);
            accoB[t4v] = MFMA32_F16(vv1, pfB1, accoB[t4v]);
        }
        laccA = MFMA32_F16(ones, pfA1, laccA);
        laccB = MFMA32_F16(ones, pfB1, laccB);
        __builtin_amdgcn_s_setprio(0);

        // ---- counted-vmcnt sync: wait own tile-(t+1) loads only; t+2's stay in flight ----
        if (t + 2 < NSTEP) {
            asm volatile("s_waitcnt vmcnt(4)" ::: "memory");
        } else {
            asm volatile("s_waitcnt vmcnt(0)" ::: "memory");
        }
        __builtin_amdgcn_s_barrier();
        __builtin_amdgcn_sched_barrier(0);

        // rotate ring: (pr, pn, pw) <- (pn, pw, pr)
        char* tk = krp; krp = knp; knp = kwp; kwp = tk;
        char* tv = vrp; vrp = vnp; vnp = vwp; vwp = tv;
    }

    // ---- epilogue: lacc holds the complete denominators ----
    {
        const int qrowA = qp * 128 + w * 16 + li;
        const float ia = 1.f / laccA[0];
        const float ib = 1.f / laccB[0];
        float* oa = Og + (size_t)qrowA * DH;
        float* ob = oa + 64 * DH;
        #pragma unroll
        for (int t4 = 0; t4 < 4; ++t4) {
            f32x4 o1, o2;
            #pragma unroll
            for (int r = 0; r < 4; ++r) { o1[r] = accoA[t4][r] * ia; o2[r] = accoB[t4][r] * ib; }
            *(f32x4*)(oa + t4 * 16 + lg * 4) = o1;
            *(f32x4*)(ob + t4 * 16 + lg * 4) = o2;
        }
    }
}

// ---------------- fallback (fp32-input, used only if ws too small) ----------------
__global__ __launch_bounds__(256)
void attn_fwd_kernel(const float* __restrict__ Qg0,
                     const float* __restrict__ Kg0,
                     const float* __restrict__ Vg0,
                     float* __restrict__ Og0)
{
    constexpr int VT_P = 72;
    constexpr int P_PB = 72;
    __shared__ __align__(16) __bf16 sKh[KBLK * DH];
    __shared__ __align__(16) __bf16 sKl[KBLK * DH];
    __shared__ __align__(16) __bf16 sVt[DH * VT_P];
    __shared__ __align__(16) __bf16 sP[4][16 * P_PB];

    const int tid  = threadIdx.x;
    const int lane = tid & 63;
    const int w    = tid >> 6;
    const int lg   = lane >> 4;
    const int li   = lane & 15;

    const int n   = blockIdx.x;
    const int xcd = n & 7;
    const int m   = n >> 3;
    const int bh  = xcd * 8 + (m >> 5);
    const int qt  = m & 31;

    const float* Qg = Qg0 + (size_t)bh * S_LEN * DH;
    const float* Kg = Kg0 + (size_t)bh * S_LEN * DH;
    const float* Vg = Vg0 + (size_t)bh * S_LEN * DH;
    float*       Og = Og0 + (size_t)bh * S_LEN * DH;

    bf16x8 qh[2], ql[2];
    {
        const int qrow = qt * 64 + w * 16 + li;
        const float* qp = Qg + (size_t)qrow * DH;
        #pragma unroll
        for (int f = 0; f < 2; ++f) {
            const int dbase = f * 32 + lg * 8;
            #pragma unroll
            for (int j = 0; j < 8; ++j) {
                float q = qp[dbase + j];
                __bf16 h = (__bf16)q;
                qh[f][j] = h;
                ql[f][j] = (__bf16)(q - (float)h);
            }
        }
    }

    f32x4 acco[4];
    #pragma unroll
    for (int t = 0; t < 4; ++t) acco[t] = f32x4{0.f, 0.f, 0.f, 0.f};
    float mval[4], lval[4];
    #pragma unroll
    for (int r = 0; r < 4; ++r) { mval[r] = -INFINITY; lval[r] = 0.f; }

    for (int step = 0; step < NSTEP; ++step) {
        __syncthreads();
        {
            const int kv0 = step * KBLK;
            #pragma unroll
            for (int i = 0; i < 4; ++i) {
                const int f4 = tid + i * 256;
                const int kv = f4 >> 4;
                const int d4 = (f4 & 15) << 2;
                f32x4 kvec = *(const f32x4*)(Kg + (size_t)(kv0 + kv) * DH + d4);
                bf16x4 h, l;
                #pragma unroll
                for (int j = 0; j < 4; ++j) {
                    __bf16 hh = (__bf16)kvec[j];
                    h[j] = hh;
                    l[j] = (__bf16)(kvec[j] - (float)hh);
                }
                const int idx = (kv * DH + d4) ^ ((kv & 7) << 3);
                *(bf16x4*)&sKh[idx] = h;
                *(bf16x4*)&sKl[idx] = l;
                f32x4 vvec = *(const f32x4*)(Vg + (size_t)(kv0 + kv) * DH + d4);
                #pragma unroll
                for (int j = 0; j < 4; ++j)
                    sVt[(d4 + j) * VT_P + kv] = (__bf16)vvec[j];
            }
        }
        __syncthreads();

        f32x4 accs[4];
        #pragma unroll
        for (int t4 = 0; t4 < 4; ++t4) {
            f32x4 acc = f32x4{0.f, 0.f, 0.f, 0.f};
            const int row = t4 * 16 + li;
            #pragma unroll
            for (int f = 0; f < 2; ++f) {
                const int idx = (row * DH + f * 32 + lg * 8) ^ ((row & 7) << 3);
                bf16x8 kh = *(const bf16x8*)&sKh[idx];
                bf16x8 kl = *(const bf16x8*)&sKl[idx];
                acc = MFMA_BF16(qh[f], kh, acc);
                acc = MFMA_BF16(qh[f], kl, acc);
                acc = MFMA_BF16(ql[f], kh, acc);
            }
            accs[t4] = acc;
        }

        #pragma unroll
        for (int r = 0; r < 4; ++r) {
            float mx = fmaxf(fmaxf(accs[0][r], accs[1][r]), fmaxf(accs[2][r], accs[3][r]));
            #pragma unroll
            for (int msk = 1; msk <= 8; msk <<= 1)
                mx = fmaxf(mx, __shfl_xor(mx, msk));
            const float newm  = fmaxf(mval[r], mx);
            const float scale = __expf(mval[r] - newm);
            mval[r] = newm;
            lval[r] *= scale;
            #pragma unroll
            for (int t4 = 0; t4 < 4; ++t4) acco[t4][r] *= scale;
            float s = 0.f;
            #pragma unroll
            for (int t4 = 0; t4 < 4; ++t4) {
                float p = __expf(accs[t4][r] - newm);
                accs[t4][r] = p;
                s += p;
            }
            #pragma unroll
            for (int msk = 1; msk <= 8; msk <<= 1)
                s += __shfl_xor(s, msk);
            lval[r] += s;
        }

        #pragma unroll
        for (int r = 0; r < 4; ++r) {
            const int rr = lg * 4 + r;
            #pragma unroll
            for (int t4 = 0; t4 < 4; ++t4)
                sP[w][rr * P_PB + t4 * 16 + li] = (__bf16)accs[t4][r];
        }

        bf16x8 pa[2];
        #pragma unroll
        for (int f = 0; f < 2; ++f)
            pa[f] = *(const bf16x8*)&sP[w][li * P_PB + f * 32 + lg * 8];
        #pragma unroll
        for (int t4 = 0; t4 < 4; ++t4) {
            #pragma unroll
            for (int f = 0; f < 2; ++f) {
                bf16x8 vb = *(const bf16x8*)&sVt[(t4 * 16 + li) * VT_P + f * 32 + lg * 8];
                acco[t4] = MFMA_BF16(pa[f], vb, acco[t4]);
            }
        }
    }

    {
        const int qrow0 = qt * 64 + w * 16;
        #pragma unroll
        for (int r = 0; r < 4; ++r) {
            const int rr = lg * 4 + r;
            const float inv = 1.f / lval[r];
            #pragma unroll
            for (int t4 = 0; t4 < 4; ++t4)
                Og[(size_t)(qrow0 + rr) * DH + t4 * 16 + li] = acco[t4][r] * inv;
        }
    }
}

extern "C" void kernel_launch(void* const* d_in, const int* in_sizes, int n_in,
                              void* d_out, int out_size, void* d_ws, size_t ws_size,
                              hipStream_t stream) {
    const float* Q = (const float*)d_in[0];
    const float* K = (const float*)d_in[1];
    const float* V = (const float*)d_in[2];
    float* O = (float*)d_out;
    if (ws_size >= WS_NEED) {
        prep_kernel<<<dim3(2048), dim3(256), 0, stream>>>(K, V, (unsigned char*)d_ws);
        attn_main<<<dim3(1024), dim3(256), 0, stream>>>(Q, (const unsigned char*)d_ws, O);
    } else {
        attn_fwd_kernel<<<dim3(2048), dim3(256), 0, stream>>>(Q, K, V, O);
    }
}

// Round 20
// 100.595 us; speedup vs baseline: 1.0482x; 1.0482x over previous
//
#include <hip/hip_runtime.h>
#include <hip/hip_bf16.h>
#include <math.h>

typedef _Float16 f16x8 __attribute__((ext_vector_type(8)));
typedef _Float16 f16x4 __attribute__((ext_vector_type(4)));
typedef __fp16   hf4  __attribute__((ext_vector_type(4)));
typedef float    f32x4 __attribute__((ext_vector_type(4)));
typedef __bf16   bf16x8 __attribute__((ext_vector_type(8)));
typedef __bf16   bf16x4 __attribute__((ext_vector_type(4)));

#define MFMA32_F16(a,b,c)  __builtin_amdgcn_mfma_f32_16x16x32_f16((a),(b),(c),0,0,0)
#define MFMA_BF16(a,b,c)   __builtin_amdgcn_mfma_f32_16x16x32_bf16((a),(b),(c),0,0,0)

constexpr int S_LEN = 2048;
constexpr int DH    = 64;
constexpr int KBLK  = 64;
constexpr int NSTEP = S_LEN / KBLK;       // 32
constexpr float LOG2E = 1.44269504088896340736f;
constexpr size_t TILE_BYTES = 16384;      // 8KB K + 8KB V-frag per tile
constexpr size_t WS_NEED = 64ull * NSTEP * TILE_BYTES;  // 33.55 MB

__device__ __forceinline__ void gload16(const void* g, void* l) {
    __builtin_amdgcn_global_load_lds(
        (const __attribute__((address_space(1))) void*)g,
        (__attribute__((address_space(3))) void*)l, 16, 0, 0);
}

__device__ __forceinline__ float exp2_fast(float x) {
    float r;
    asm("v_exp_f32 %0, %1" : "=v"(r) : "v"(x));
    return r;
}

// reductions across the 4 lane-groups holding one q-row (l^16, l^32)
__device__ __forceinline__ float redmax_lg(float x) {
    x = fmaxf(x, __shfl_xor(x, 16));
    x = fmaxf(x, __shfl_xor(x, 32));
    return x;
}

__device__ __forceinline__ f16x4 as_f16x4(hf4 h) {
    f16x4 f;
    __builtin_memcpy(&f, &h, 8);
    return f;
}

// ---------------- pre-pass: K -> fp16 swizzled rows; V -> permuted-k A-fragments ----------------
// K tile (8KB): row-major, byte (row*128 + d*2) ^ ((row&7)<<4)
// V tile (8KB): chunk16B[(p*4+lg)*1024 + d*16]: halves[j] = V[p*32 + (j>>2)*16 + lg*4 + (j&3)][d]
//   == A-fragment of 16x16x32 MFMA under shared k-map k(lg,j) = (j>>2)*16 + lg*4 + (j&3)
__global__ __launch_bounds__(256)
void prep_kernel(const float* __restrict__ Kg, const float* __restrict__ Vg,
                 unsigned char* __restrict__ ws)
{
    __shared__ _Float16 sT[64 * 70];   // V tile staging, pitch 70 halfs

    const int blk = blockIdx.x;        // bh*32 + tile
    const int tid = threadIdx.x;
    const float* Kt = Kg + (size_t)blk * KBLK * DH;
    const float* Vt = Vg + (size_t)blk * KBLK * DH;
    char* wK = (char*)(ws + (size_t)blk * TILE_BYTES);
    char* wV = wK + 8192;

    #pragma unroll
    for (int c = 0; c < 2; ++c) {
        const int eid = tid + c * 256;         // 0..511 chunks of 8 elems
        const int row = eid >> 3;
        const int d0  = (eid & 7) * 8;
        // K: convert + pre-swizzled row-major tile
        f32x4 a = *(const f32x4*)(Kt + row * DH + d0);
        f32x4 b = *(const f32x4*)(Kt + row * DH + d0 + 4);
        f16x8 h;
        #pragma unroll
        for (int j = 0; j < 4; ++j) { h[j] = (_Float16)a[j]; h[4 + j] = (_Float16)b[j]; }
        const int koff = (row * 128 + d0 * 2) ^ ((row & 7) << 4);
        *(f16x8*)(wK + koff) = h;
        // V: convert into LDS row-major (pitch 70)
        f32x4 va = *(const f32x4*)(Vt + row * DH + d0);
        f32x4 vb = *(const f32x4*)(Vt + row * DH + d0 + 4);
        #pragma unroll
        for (int j = 0; j < 4; ++j) {
            sT[row * 70 + d0 + j]     = (_Float16)va[j];
            sT[row * 70 + d0 + 4 + j] = (_Float16)vb[j];
        }
    }
    __syncthreads();
    // build permuted-k V-fragment chunks
    #pragma unroll
    for (int c = 0; c < 2; ++c) {
        const int id  = tid + c * 256;   // 0..511
        const int p   = id >> 8;         // 0..1
        const int lgc = (id >> 6) & 3;   // 0..3
        const int d   = id & 63;
        const int kv0 = p * 32 + lgc * 4;
        f16x8 h;
        #pragma unroll
        for (int j = 0; j < 4; ++j) {
            h[j]     = sT[(kv0 + j) * 70 + d];
            h[4 + j] = sT[(kv0 + 16 + j) * 70 + d];
        }
        *(f16x8*)(wV + (p * 4 + lgc) * 1024 + d * 16) = h;
    }
}

// ---------------- main: flash attention, 2 q-tiles/block, K=32 PV, ones-MFMA l-sum ----------------
__global__ __launch_bounds__(256, 4)
void attn_main(const float* __restrict__ Qg0, const unsigned char* __restrict__ ws,
               float* __restrict__ Og0)
{
    __shared__ __align__(16) _Float16 sK[2][KBLK * DH];   // 16 KB
    __shared__ __align__(16) _Float16 sV[2][KBLK * DH];   // 16 KB  (total 32768)

    const int tid  = threadIdx.x;
    const int lane = tid & 63;
    const int w    = tid >> 6;
    const int lg   = lane >> 4;
    const int li   = lane & 15;
    const int X    = (li & 7) << 4;    // K-read XOR swizzle key

    // 1024 blocks = 8 xcd * 8 bh * 16 qpairs
    const int n   = blockIdx.x;
    const int xcd = n & 7;
    const int m_  = n >> 3;            // 0..127
    const int bh  = xcd * 8 + (m_ >> 4);
    const int qp  = m_ & 15;

    const float* Qg = Qg0 + (size_t)bh * S_LEN * DH;
    float*       Og = Og0 + (size_t)bh * S_LEN * DH;
    const unsigned char* wsb = ws + (size_t)bh * NSTEP * TILE_BYTES;

    // Q fragments (fp16), pre-scaled by log2(e); two q-tiles A/B
    f16x8 qA[2], qB[2];
    {
        const int qrowA = qp * 128 + w * 16 + li;
        const float* pa = Qg + (size_t)qrowA * DH;
        const float* pb = pa + 64 * DH;
        #pragma unroll
        for (int f = 0; f < 2; ++f) {
            f32x4 a0 = *(const f32x4*)(pa + f * 32 + lg * 8);
            f32x4 a1 = *(const f32x4*)(pa + f * 32 + lg * 8 + 4);
            f32x4 b0 = *(const f32x4*)(pb + f * 32 + lg * 8);
            f32x4 b1 = *(const f32x4*)(pb + f * 32 + lg * 8 + 4);
            #pragma unroll
            for (int j = 0; j < 4; ++j) {
                qA[f][j]     = (_Float16)(a0[j] * LOG2E);
                qA[f][4 + j] = (_Float16)(a1[j] * LOG2E);
                qB[f][j]     = (_Float16)(b0[j] * LOG2E);
                qB[f][4 + j] = (_Float16)(b1[j] * LOG2E);
            }
        }
    }

    // all-ones A-fragment: layout-independent; MFMA(ones, pf, lacc) sums P over kv
    f16x8 ones;
    #pragma unroll
    for (int j = 0; j < 8; ++j) ones[j] = (_Float16)1.0f;

    f32x4 accoA[4], accoB[4];
    #pragma unroll
    for (int t = 0; t < 4; ++t) {
        accoA[t] = f32x4{0.f, 0.f, 0.f, 0.f};
        accoB[t] = f32x4{0.f, 0.f, 0.f, 0.f};
    }
    float mA = 0.f, mB = 0.f;
    f32x4 laccA = {0.f, 0.f, 0.f, 0.f};   // denominator accumulator (every element = full row sum)
    f32x4 laccB = {0.f, 0.f, 0.f, 0.f};

    auto stage = [&](int buf, int t) {
        const unsigned char* src = wsb + (size_t)t * TILE_BYTES;
        char* lk = (char*)&sK[buf][0] + w * 2048;
        char* lv = (char*)&sV[buf][0] + w * 2048;
        const unsigned char* gk = src + w * 2048 + lane * 16;
        const unsigned char* gv = src + 8192 + w * 2048 + lane * 16;
        gload16(gk,        lk);
        gload16(gk + 1024, lk + 1024);
        gload16(gv,        lv);
        gload16(gv + 1024, lv + 1024);
    };

    stage(0, 0);
    __syncthreads();
    int buf = 0;

    for (int t = 0; t < NSTEP; ++t) {
        if (t + 1 < NSTEP) stage(buf ^ 1, t + 1);

        const char* kb = (const char*)&sK[buf][0];
        const char* vb = (const char*)&sV[buf][0];

        // ---- S^T - m = K Q^T + (-m) ----
        f32x4 sA[4], sB[4];
        const f32x4 cA = {-mA, -mA, -mA, -mA};
        const f32x4 cB = {-mB, -mB, -mB, -mB};
        __builtin_amdgcn_s_setprio(1);
        #pragma unroll
        for (int t4 = 0; t4 < 4; ++t4) {
            const char* kr = kb + t4 * 2048 + li * 128;
            f16x8 kf0 = *(const f16x8*)(kr + ((0 * 64 + lg * 16) ^ X));
            f16x8 kf1 = *(const f16x8*)(kr + ((1 * 64 + lg * 16) ^ X));
            f32x4 a = MFMA32_F16(kf0, qA[0], cA);
            a       = MFMA32_F16(kf1, qA[1], a);
            f32x4 b = MFMA32_F16(kf0, qB[0], cB);
            b       = MFMA32_F16(kf1, qB[1], b);
            sA[t4] = a;
            sB[t4] = b;
        }
        __builtin_amdgcn_s_setprio(0);

        // ---- lane-local max of biased scores (16 kv each) ----
        float mlA = fmaxf(fmaxf(fmaxf(sA[0][0], sA[0][1]), sA[0][2]),
                          fmaxf(fmaxf(sA[0][3], sA[1][0]), sA[1][1]));
        mlA = fmaxf(mlA, fmaxf(fmaxf(sA[1][2], sA[1][3]), sA[2][0]));
        mlA = fmaxf(mlA, fmaxf(fmaxf(sA[2][1], sA[2][2]), sA[2][3]));
        mlA = fmaxf(mlA, fmaxf(fmaxf(sA[3][0], sA[3][1]), fmaxf(sA[3][2], sA[3][3])));
        float mlB = fmaxf(fmaxf(fmaxf(sB[0][0], sB[0][1]), sB[0][2]),
                          fmaxf(fmaxf(sB[0][3], sB[1][0]), sB[1][1]));
        mlB = fmaxf(mlB, fmaxf(fmaxf(sB[1][2], sB[1][3]), sB[2][0]));
        mlB = fmaxf(mlB, fmaxf(fmaxf(sB[2][1], sB[2][2]), sB[2][3]));
        mlB = fmaxf(mlB, fmaxf(fmaxf(sB[3][0], sB[3][1]), fmaxf(sB[3][2], sB[3][3])));

        // ---- defer-max rescale: fires rarely; re-bias scores when it does ----
        if (__any(mlA > 8.f)) {
            const float rowmax = redmax_lg(mlA);
            const float delta  = fmaxf(rowmax, 0.f);
            const float sc     = exp2_fast(-delta);
            mA += delta;  laccA *= sc;
            #pragma unroll
            for (int t4 = 0; t4 < 4; ++t4) { accoA[t4] *= sc; sA[t4] -= delta; }
        }
        if (__any(mlB > 8.f)) {
            const float rowmax = redmax_lg(mlB);
            const float delta  = fmaxf(rowmax, 0.f);
            const float sc     = exp2_fast(-delta);
            mB += delta;  laccB *= sc;
            #pragma unroll
            for (int t4 = 0; t4 < 4; ++t4) { accoB[t4] *= sc; sB[t4] -= delta; }
        }

        // ---- exp2 + packed f16 convert (no scalar sum adds) ----
        f16x4 pA[4], pB[4];
        #pragma unroll
        for (int t4 = 0; t4 < 4; ++t4) {
            float a0 = exp2_fast(sA[t4][0]);
            float a1 = exp2_fast(sA[t4][1]);
            float a2 = exp2_fast(sA[t4][2]);
            float a3 = exp2_fast(sA[t4][3]);
            pA[t4] = as_f16x4(__builtin_shufflevector(
                __builtin_amdgcn_cvt_pkrtz(a0, a1),
                __builtin_amdgcn_cvt_pkrtz(a2, a3), 0, 1, 2, 3));
            float b0 = exp2_fast(sB[t4][0]);
            float b1 = exp2_fast(sB[t4][1]);
            float b2 = exp2_fast(sB[t4][2]);
            float b3 = exp2_fast(sB[t4][3]);
            pB[t4] = as_f16x4(__builtin_shufflevector(
                __builtin_amdgcn_cvt_pkrtz(b0, b1),
                __builtin_amdgcn_cvt_pkrtz(b2, b3), 0, 1, 2, 3));
        }

        f16x8 pfA0 = __builtin_shufflevector(pA[0], pA[1], 0, 1, 2, 3, 4, 5, 6, 7);
        f16x8 pfA1 = __builtin_shufflevector(pA[2], pA[3], 0, 1, 2, 3, 4, 5, 6, 7);
        f16x8 pfB0 = __builtin_shufflevector(pB[0], pB[1], 0, 1, 2, 3, 4, 5, 6, 7);
        f16x8 pfB1 = __builtin_shufflevector(pB[2], pB[3], 0, 1, 2, 3, 4, 5, 6, 7);

        // ---- O^T += V^T P^T, and l += sum(P) via ones-MFMA (independent chains) ----
        __builtin_amdgcn_s_setprio(1);
        laccA = MFMA32_F16(ones, pfA0, laccA);
        laccB = MFMA32_F16(ones, pfB0, laccB);
        #pragma unroll
        for (int t4v = 0; t4v < 4; ++t4v) {
            f16x8 vv0 = *(const f16x8*)(vb + lg * 1024 + t4v * 256 + li * 16);
            accoA[t4v] = MFMA32_F16(vv0, pfA0, accoA[t4v]);
            accoB[t4v] = MFMA32_F16(vv0, pfB0, accoB[t4v]);
            f16x8 vv1 = *(const f16x8*)(vb + 4096 + lg * 1024 + t4v * 256 + li * 16);
            accoA[t4v] = MFMA32_F16(vv1, pfA1, accoA[t4v]);
            accoB[t4v] = MFMA32_F16(vv1, pfB1, accoB[t4v]);
        }
        laccA = MFMA32_F16(ones, pfA1, laccA);
        laccB = MFMA32_F16(ones, pfB1, laccB);
        __builtin_amdgcn_s_setprio(0);

        __syncthreads();
        buf ^= 1;
    }

    // ---- epilogue: lacc holds the complete denominators ----
    {
        const int qrowA = qp * 128 + w * 16 + li;
        const float ia = 1.f / laccA[0];
        const float ib = 1.f / laccB[0];
        float* oa = Og + (size_t)qrowA * DH;
        float* ob = oa + 64 * DH;
        #pragma unroll
        for (int t4 = 0; t4 < 4; ++t4) {
            f32x4 o1, o2;
            #pragma unroll
            for (int r = 0; r < 4; ++r) { o1[r] = accoA[t4][r] * ia; o2[r] = accoB[t4][r] * ib; }
            *(f32x4*)(oa + t4 * 16 + lg * 4) = o1;
            *(f32x4*)(ob + t4 * 16 + lg * 4) = o2;
        }
    }
}

// ---------------- fallback (fp32-input, used only if ws too small) ----------------
__global__ __launch_bounds__(256)
void attn_fwd_kernel(const float* __restrict__ Qg0,
                     const float* __restrict__ Kg0,
                     const float* __restrict__ Vg0,
                     float* __restrict__ Og0)
{
    constexpr int VT_P = 72;
    constexpr int P_PB = 72;
    __shared__ __align__(16) __bf16 sKh[KBLK * DH];
    __shared__ __align__(16) __bf16 sKl[KBLK * DH];
    __shared__ __align__(16) __bf16 sVt[DH * VT_P];
    __shared__ __align__(16) __bf16 sP[4][16 * P_PB];

    const int tid  = threadIdx.x;
    const int lane = tid & 63;
    const int w    = tid >> 6;
    const int lg   = lane >> 4;
    const int li   = lane & 15;

    const int n   = blockIdx.x;
    const int xcd = n & 7;
    const int m   = n >> 3;
    const int bh  = xcd * 8 + (m >> 5);
    const int qt  = m & 31;

    const float* Qg = Qg0 + (size_t)bh * S_LEN * DH;
    const float* Kg = Kg0 + (size_t)bh * S_LEN * DH;
    const float* Vg = Vg0 + (size_t)bh * S_LEN * DH;
    float*       Og = Og0 + (size_t)bh * S_LEN * DH;

    bf16x8 qh[2], ql[2];
    {
        const int qrow = qt * 64 + w * 16 + li;
        const float* qp = Qg + (size_t)qrow * DH;
        #pragma unroll
        for (int f = 0; f < 2; ++f) {
            const int dbase = f * 32 + lg * 8;
            #pragma unroll
            for (int j = 0; j < 8; ++j) {
                float q = qp[dbase + j];
                __bf16 h = (__bf16)q;
                qh[f][j] = h;
                ql[f][j] = (__bf16)(q - (float)h);
            }
        }
    }

    f32x4 acco[4];
    #pragma unroll
    for (int t = 0; t < 4; ++t) acco[t] = f32x4{0.f, 0.f, 0.f, 0.f};
    float mval[4], lval[4];
    #pragma unroll
    for (int r = 0; r < 4; ++r) { mval[r] = -INFINITY; lval[r] = 0.f; }

    for (int step = 0; step < NSTEP; ++step) {
        __syncthreads();
        {
            const int kv0 = step * KBLK;
            #pragma unroll
            for (int i = 0; i < 4; ++i) {
                const int f4 = tid + i * 256;
                const int kv = f4 >> 4;
                const int d4 = (f4 & 15) << 2;
                f32x4 kvec = *(const f32x4*)(Kg + (size_t)(kv0 + kv) * DH + d4);
                bf16x4 h, l;
                #pragma unroll
                for (int j = 0; j < 4; ++j) {
                    __bf16 hh = (__bf16)kvec[j];
                    h[j] = hh;
                    l[j] = (__bf16)(kvec[j] - (float)hh);
                }
                const int idx = (kv * DH + d4) ^ ((kv & 7) << 3);
                *(bf16x4*)&sKh[idx] = h;
                *(bf16x4*)&sKl[idx] = l;
                f32x4 vvec = *(const f32x4*)(Vg + (size_t)(kv0 + kv) * DH + d4);
                #pragma unroll
                for (int j = 0; j < 4; ++j)
                    sVt[(d4 + j) * VT_P + kv] = (__bf16)vvec[j];
            }
        }
        __syncthreads();

        f32x4 accs[4];
        #pragma unroll
        for (int t4 = 0; t4 < 4; ++t4) {
            f32x4 acc = f32x4{0.f, 0.f, 0.f, 0.f};
            const int row = t4 * 16 + li;
            #pragma unroll
            for (int f = 0; f < 2; ++f) {
                const int idx = (row * DH + f * 32 + lg * 8) ^ ((row & 7) << 3);
                bf16x8 kh = *(const bf16x8*)&sKh[idx];
                bf16x8 kl = *(const bf16x8*)&sKl[idx];
                acc = MFMA_BF16(qh[f], kh, acc);
                acc = MFMA_BF16(qh[f], kl, acc);
                acc = MFMA_BF16(ql[f], kh, acc);
            }
            accs[t4] = acc;
        }

        #pragma unroll
        for (int r = 0; r < 4; ++r) {
            float mx = fmaxf(fmaxf(accs[0][r], accs[1][r]), fmaxf(accs[2][r], accs[3][r]));
            #pragma unroll
            for (int msk = 1; msk <= 8; msk <<= 1)
                mx = fmaxf(mx, __shfl_xor(mx, msk));
            const float newm  = fmaxf(mval[r], mx);
            const float scale = __expf(mval[r] - newm);
            mval[r] = newm;
            lval[r] *= scale;
            #pragma unroll
            for (int t4 = 0; t4 < 4; ++t4) acco[t4][r] *= scale;
            float s = 0.f;
            #pragma unroll
            for (int t4 = 0; t4 < 4; ++t4) {
                float p = __expf(accs[t4][r] - newm);
                accs[t4][r] = p;
                s += p;
            }
            #pragma unroll
            for (int msk = 1; msk <= 8; msk <<= 1)
                s += __shfl_xor(s, msk);
            lval[r] += s;
        }

        #pragma unroll
        for (int r = 0; r < 4; ++r) {
            const int rr = lg * 4 + r;
            #pragma unroll
            for (int t4 = 0; t4 < 4; ++t4)
                sP[w][rr * P_PB + t4 * 16 + li] = (__bf16)accs[t4][r];
        }

        bf16x8 pa[2];
        #pragma unroll
        for (int f = 0; f < 2; ++f)
            pa[f] = *(const bf16x8*)&sP[w][li * P_PB + f * 32 + lg * 8];
        #pragma unroll
        for (int t4 = 0; t4 < 4; ++t4) {
            #pragma unroll
            for (int f = 0; f < 2; ++f) {
                bf16x8 vb = *(const bf16x8*)&sVt[(t4 * 16 + li) * VT_P + f * 32 + lg * 8];
                acco[t4] = MFMA_BF16(pa[f], vb, acco[t4]);
            }
        }
    }

    {
        const int qrow0 = qt * 64 + w * 16;
        #pragma unroll
        for (int r = 0; r < 4; ++r) {
            const int rr = lg * 4 + r;
            const float inv = 1.f / lval[r];
            #pragma unroll
            for (int t4 = 0; t4 < 4; ++t4)
                Og[(size_t)(qrow0 + rr) * DH + t4 * 16 + li] = acco[t4][r] * inv;
        }
    }
}

extern "C" void kernel_launch(void* const* d_in, const int* in_sizes, int n_in,
                              void* d_out, int out_size, void* d_ws, size_t ws_size,
                              hipStream_t stream) {
    const float* Q = (const float*)d_in[0];
    const float* K = (const float*)d_in[1];
    const float* V = (const float*)d_in[2];
    float* O = (float*)d_out;
    if (ws_size >= WS_NEED) {
        prep_kernel<<<dim3(2048), dim3(256), 0, stream>>>(K, V, (unsigned char*)d_ws);
        attn_main<<<dim3(1024), dim3(256), 0, stream>>>(Q, (const unsigned char*)d_ws, O);
    } else {
        attn_fwd_kernel<<<dim3(2048), dim3(256), 0, stream>>>(Q, K, V, O);
    }
}